// Round 1
// baseline (9603.155 us; speedup 1.0000x reference)
//
#include <hip/hip_runtime.h>

// ---------------------------------------------------------------------------
// RNN scan on MI355X.
//   Phase P: pack W_w and U_w into f16-pair (u32) layouts.
//   Phase G: wx[b,t,:] = x[b,t,:]@W_w + W_b  (f16-dot2 GEMM, packed-u32 out)
//   Phase R: per-batch persistent workgroup scan. U resident on-chip:
//            k in [0,384) in VGPRs (192 uint2/thread), k in [384,512) in LDS.
//            h kept as packed f16 in LDS, broadcast-read as uint4.
// ---------------------------------------------------------------------------

#define NREG 192          // U k-pairs resident in VGPRs  (k in [0,384))
#define NTAIL 64          // U k-pairs resident in LDS    (k in [384,512))

typedef _Float16 h2_t __attribute__((ext_vector_type(2)));
union U32H2 { unsigned u; h2_t h; _Float16 f[2]; };

__device__ inline unsigned pkf16(float a, float b){
  U32H2 v; v.f[0] = (_Float16)a; v.f[1] = (_Float16)b; return v.u;
}

__device__ inline float dot2(unsigned a, unsigned b, float c){
  U32H2 x, y; x.u = a; y.u = b;
#if __has_builtin(__builtin_amdgcn_fdot2)
  return __builtin_amdgcn_fdot2(x.h, y.h, c, false);   // v_dot2_f32_f16
#else
  return c + (float)x.f[0]*(float)y.f[0] + (float)x.f[1]*(float)y.f[1];
#endif
}

// ---------------------------------------------------------------------------
// P: pack weights. 256 blocks x 256 threads = 65536 threads, one elem each.
// ---------------------------------------------------------------------------
__global__ __launch_bounds__(256) void prep_pack(const float* __restrict__ Ww,
                                                 const float* __restrict__ Uw,
                                                 unsigned* __restrict__ Wp,
                                                 uint2* __restrict__ Ur,
                                                 uint2* __restrict__ Ut){
  int idx = blockIdx.x*256 + threadIdx.x;
  { // Wpack[kp][j], kp<128, j<512 : pairs (2kp,2kp+1) of column j
    int kp = idx >> 9, j = idx & 511;
    Wp[idx] = pkf16(Ww[(2*kp)*512 + j], Ww[(2*kp+1)*512 + j]);
  }
  if (idx < NREG*256){ // Ureg[kp][t] = {col t, col t+256}
    int kp = idx >> 8, t = idx & 255;
    uint2 v;
    v.x = pkf16(Uw[(2*kp)*512 + t],       Uw[(2*kp+1)*512 + t]);
    v.y = pkf16(Uw[(2*kp)*512 + t + 256], Uw[(2*kp+1)*512 + t + 256]);
    Ur[idx] = v;
  }
  if (idx < NTAIL*256){ // Utail[r][t], k0 = 384+2r
    int r = idx >> 8, t = idx & 255;
    int k0 = 2*NREG + 2*r;
    uint2 v;
    v.x = pkf16(Uw[k0*512 + t],       Uw[(k0+1)*512 + t]);
    v.y = pkf16(Uw[k0*512 + t + 256], Uw[(k0+1)*512 + t + 256]);
    Ut[idx] = v;
  }
}

// ---------------------------------------------------------------------------
// G: wx GEMM. Block = 32 seq rows x 512 cols; thread owns cols (tid, tid+256)
// so the packed-u32 output pairs line up exactly with phase R's per-thread
// column ownership. 4096 blocks.
// ---------------------------------------------------------------------------
__global__ __launch_bounds__(256) void gemm_wx(const float* __restrict__ x,
                                               const unsigned* __restrict__ Wp,
                                               const float* __restrict__ Wb,
                                               unsigned* __restrict__ wxp){
  __shared__ unsigned xt[32][128];      // x tile, packed f16 pairs, 16 KB
  const int tid = threadIdx.x;
  const int b = blockIdx.x >> 6, sb = blockIdx.x & 63;
  const float* xrow = x + ((size_t)(b*2048 + sb*32))*256;
  #pragma unroll
  for (int i=0;i<8;i++){
    int f = i*256 + tid;                // 2048 float4 total
    int r = f >> 6, c4 = f & 63;
    float4 v = ((const float4*)xrow)[r*64 + c4];
    xt[r][2*c4]   = pkf16(v.x, v.y);
    xt[r][2*c4+1] = pkf16(v.z, v.w);
  }
  float acc0[32], acc1[32];
  #pragma unroll
  for (int r=0;r<32;r++){ acc0[r]=0.f; acc1[r]=0.f; }
  __syncthreads();
  #pragma unroll 4
  for (int kp=0;kp<128;kp++){
    unsigned w0 = Wp[kp*512 + tid];
    unsigned w1 = Wp[kp*512 + tid + 256];
    #pragma unroll
    for (int r=0;r<32;r++){
      unsigned xv = xt[r][kp];          // LDS broadcast
      acc0[r] = dot2(xv, w0, acc0[r]);
      acc1[r] = dot2(xv, w1, acc1[r]);
    }
  }
  float wb0 = Wb[tid], wb1 = Wb[tid+256];
  unsigned* o = wxp + ((size_t)(b*2048 + sb*32))*256;
  #pragma unroll
  for (int r=0;r<32;r++)
    o[r*256 + tid] = pkf16(acc0[r]+wb0, acc1[r]+wb1);
}

// ---------------------------------------------------------------------------
// R: the sequential scan. 64 blocks (one per batch) x 256 threads.
// Thread tid owns output columns tid and tid+256.
// VGPR budget: 192 uint2 U-regs = 384 VGPRs + ~30 working, 1 block/CU.
// LDS: U tail 128 KB + h 1 KB.
// ---------------------------------------------------------------------------
__global__ __launch_bounds__(256,1) void rnn_scan(const uint2* __restrict__ Ur,
                                                  const uint2* __restrict__ Ut,
                                                  const unsigned* __restrict__ wxp,
                                                  const float* __restrict__ Ub,
                                                  const float* __restrict__ Vw,
                                                  const float* __restrict__ Vb,
                                                  float* __restrict__ out){
  __shared__ __align__(16) _Float16 harr[512];   // h as f16, read as uint4
  __shared__ uint2 utail[NTAIL*256];             // 128 KB
  __shared__ float rbuf[8];
  const int tid = threadIdx.x;
  const int b = blockIdx.x;

  uint2 ureg[NREG];
  #pragma unroll
  for (int i=0;i<NREG;i++) ureg[i] = Ur[i*256 + tid];
  #pragma unroll
  for (int i=0;i<NTAIL;i++) utail[i*256 + tid] = Ut[i*256 + tid];
  harr[tid]     = (_Float16)0.f;                 // h0 = 0
  harr[tid+256] = (_Float16)0.f;
  const float ub0 = Ub[tid], ub1 = Ub[tid+256];
  const unsigned* wxb = wxp + (size_t)b*2048*256;
  unsigned wc = wxb[tid];                        // wx[t=0] (distance-2 pipe)
  unsigned wn = wxb[256 + tid];                  // wx[t=1]
  __syncthreads();
  const uint4* hq = (const uint4*)harr;
  float h0f = 0.f, h1f = 0.f;

  #pragma unroll 1
  for (int t=0;t<2048;t++){
    U32H2 wv; wv.u = wc;
    float c0a = (float)wv.f[0] + ub0;            // 4 chains for VALU latency
    float c1a = (float)wv.f[1] + ub1;
    float c0b = 0.f, c1b = 0.f;
    wc = wn;
    int tn = (t+2 < 2048) ? (t+2) : 2047;
    wn = wxb[tn*256 + tid];                      // prefetch wx[t+2]

    #pragma unroll
    for (int q=0;q<NREG/4;q++){                  // k in [0,384): U from VGPRs
      uint4 hv = hq[q];                          // 8 h values, broadcast b128
      uint2 u0 = ureg[4*q+0], u1 = ureg[4*q+1];
      uint2 u2 = ureg[4*q+2], u3 = ureg[4*q+3];
      c0a = dot2(u0.x, hv.x, c0a);  c1a = dot2(u0.y, hv.x, c1a);
      c0b = dot2(u1.x, hv.y, c0b);  c1b = dot2(u1.y, hv.y, c1b);
      c0a = dot2(u2.x, hv.z, c0a);  c1a = dot2(u2.y, hv.z, c1a);
      c0b = dot2(u3.x, hv.w, c0b);  c1b = dot2(u3.y, hv.w, c1b);
    }
    #pragma unroll
    for (int q=0;q<NTAIL/4;q++){                 // k in [384,512): U from LDS
      uint4 hv = hq[NREG/4 + q];
      uint2 u0 = utail[(4*q+0)*256+tid], u1 = utail[(4*q+1)*256+tid];
      uint2 u2 = utail[(4*q+2)*256+tid], u3 = utail[(4*q+3)*256+tid];
      c0a = dot2(u0.x, hv.x, c0a);  c1a = dot2(u0.y, hv.x, c1a);
      c0b = dot2(u1.x, hv.y, c0b);  c1b = dot2(u1.y, hv.y, c1b);
      c0a = dot2(u2.x, hv.z, c0a);  c1a = dot2(u2.y, hv.z, c1a);
      c0b = dot2(u3.x, hv.w, c0b);  c1b = dot2(u3.y, hv.w, c1b);
    }
    float p0 = c0a + c0b, p1 = c1a + c1b;
    // tanh(x) = 1 - 2/(e^{2x}+1): saturates correctly at +-1, no NaN
    h0f = 1.f - 2.f/(__expf(2.f*p0) + 1.f);
    h1f = 1.f - 2.f/(__expf(2.f*p1) + 1.f);
    __syncthreads();                             // all reads of h done
    harr[tid]     = (_Float16)h0f;
    harr[tid+256] = (_Float16)h1f;
    __syncthreads();                             // h visible for next step
  }

  // epilogue: o[b,c] = sigmoid(h_T @ V + Vb)
  float p0 = h0f*Vw[2*tid]   + h1f*Vw[2*(tid+256)];
  float p1 = h0f*Vw[2*tid+1] + h1f*Vw[2*(tid+256)+1];
  #pragma unroll
  for (int off=32; off>0; off>>=1){
    p0 += __shfl_down(p0, off);
    p1 += __shfl_down(p1, off);
  }
  if ((tid & 63) == 0){
    rbuf[(tid>>6)*2]   = p0;
    rbuf[(tid>>6)*2+1] = p1;
  }
  __syncthreads();
  if (tid == 0){
    float s0 = rbuf[0]+rbuf[2]+rbuf[4]+rbuf[6] + Vb[0];
    float s1 = rbuf[1]+rbuf[3]+rbuf[5]+rbuf[7] + Vb[1];
    out[2*b]   = 1.f/(1.f + __expf(-s0));
    out[2*b+1] = 1.f/(1.f + __expf(-s1));
  }
}

// ---------------------------------------------------------------------------
extern "C" void kernel_launch(void* const* d_in, const int* in_sizes, int n_in,
                              void* d_out, int out_size, void* d_ws, size_t ws_size,
                              hipStream_t stream) {
  const float* x  = (const float*)d_in[0];   // [64,2048,256]
  const float* Ww = (const float*)d_in[1];   // [256,512]
  const float* Wb = (const float*)d_in[2];   // [512]
  const float* Uw = (const float*)d_in[3];   // [512,512]
  const float* Ub = (const float*)d_in[4];   // [512]
  const float* Vw = (const float*)d_in[5];   // [512,2]
  const float* Vb = (const float*)d_in[6];   // [2]
  float* out = (float*)d_out;                // [64,2]

  char* ws = (char*)d_ws;
  // workspace layout (total ~128.8 MB)
  unsigned* wxp = (unsigned*)ws;                               // 134,217,728 B
  unsigned* Wp  = (unsigned*)(ws + 134217728);                 //     262,144 B
  uint2*    UrP = (uint2*)   (ws + 134217728 + 262144);        // NREG*256*8
  uint2*    UtP = (uint2*)   (ws + 134217728 + 262144 + (size_t)NREG*256*8);

  prep_pack<<<256, 256, 0, stream>>>(Ww, Uw, Wp, UrP, UtP);
  gemm_wx  <<<4096, 256, 0, stream>>>(x, Wp, Wb, wxp);
  rnn_scan <<<64, 256, 0, stream>>>(UrP, UtP, wxp, Ub, Vw, Vb, out);
}

// Round 2
// 3157.196 us; speedup vs baseline: 3.0417x; 3.0417x over previous
//
#include <hip/hip_runtime.h>

// ---------------------------------------------------------------------------
// RNN scan on MI355X — round 2.
// Phase R redesign: 64 blocks x 512 threads (8 waves, 2 waves/SIMD).
//   Thread t: kq = t>>7 (k-quarter, 64 pairs), cp = t&127 -> columns
//   {cp, cp+128, cp+256, cp+384}. Per thread 4 cols x 64 pairs = 256 dot2.
//   U: 48 pairs/col in arch VGPRs (192 regs, under the 256 arch cap),
//      16 pairs/col in LDS (128 KB). Partial sums reduced via LDS table.
// ---------------------------------------------------------------------------

#define NRP 48            // pairs per column resident in VGPRs (as uint4/4cols)
#define NTP 16            // pairs per column resident in LDS

typedef _Float16 h2_t __attribute__((ext_vector_type(2)));
union U32H2 { unsigned u; h2_t h; _Float16 f[2]; };

__device__ inline unsigned pkf16(float a, float b){
  U32H2 v; v.f[0] = (_Float16)a; v.f[1] = (_Float16)b; return v.u;
}

__device__ inline float dot2(unsigned a, unsigned b, float c){
  U32H2 x, y; x.u = a; y.u = b;
#if __has_builtin(__builtin_amdgcn_fdot2)
  return __builtin_amdgcn_fdot2(x.h, y.h, c, false);   // v_dot2_f32_f16
#else
  return c + (float)x.f[0]*(float)y.f[0] + (float)x.f[1]*(float)y.f[1];
#endif
}

// ---------------------------------------------------------------------------
// P: pack weights. 256 blocks x 256 threads.
//  - Wp[kp*512+j] = pack(Ww[2kp][j], Ww[2kp+1][j])              (idx < 65536)
//  - U uint4 layout for the scan: item (t,j), t<512, j<64:
//      kq=t>>7, cp=t&127, pair p=64*kq+j, cols c_e=cp+128e
//      v = { pack(U[2p][c_e], U[2p+1][c_e]) : e=0..3 }
//      j<NRP -> UrP[j*512+t] ; else UtP[(j-NRP)*512+t]
// ---------------------------------------------------------------------------
__global__ __launch_bounds__(256) void prep_pack(const float* __restrict__ Ww,
                                                 const float* __restrict__ Uw,
                                                 unsigned* __restrict__ Wp,
                                                 uint4* __restrict__ UrP,
                                                 uint4* __restrict__ UtP){
  int idx = blockIdx.x*256 + threadIdx.x;
  { // W pack
    int kp = idx >> 9, j = idx & 511;
    Wp[idx] = pkf16(Ww[(2*kp)*512 + j], Ww[(2*kp+1)*512 + j]);
  }
  if (idx < 512*64){
    int t = idx & 511, j = idx >> 9;
    int kq = t >> 7, cp = t & 127;
    int p = 64*kq + j, k0 = 2*p;
    uint4 v;
    unsigned* vv = (unsigned*)&v;
    #pragma unroll
    for (int e=0;e<4;e++){
      int c = cp + 128*e;
      vv[e] = pkf16(Uw[k0*512 + c], Uw[(k0+1)*512 + c]);
    }
    if (j < NRP) UrP[j*512 + t] = v;
    else         UtP[(j-NRP)*512 + t] = v;
  }
}

// ---------------------------------------------------------------------------
// G: wx GEMM (unchanged). Output wxp[(b*2048+s)*256 + j] = pack(col j, j+256)
// ---------------------------------------------------------------------------
__global__ __launch_bounds__(256) void gemm_wx(const float* __restrict__ x,
                                               const unsigned* __restrict__ Wp,
                                               const float* __restrict__ Wb,
                                               unsigned* __restrict__ wxp){
  __shared__ unsigned xt[32][128];      // 16 KB
  const int tid = threadIdx.x;
  const int b = blockIdx.x >> 6, sb = blockIdx.x & 63;
  const float* xrow = x + ((size_t)(b*2048 + sb*32))*256;
  #pragma unroll
  for (int i=0;i<8;i++){
    int f = i*256 + tid;
    int r = f >> 6, c4 = f & 63;
    float4 v = ((const float4*)xrow)[r*64 + c4];
    xt[r][2*c4]   = pkf16(v.x, v.y);
    xt[r][2*c4+1] = pkf16(v.z, v.w);
  }
  float acc0[32], acc1[32];
  #pragma unroll
  for (int r=0;r<32;r++){ acc0[r]=0.f; acc1[r]=0.f; }
  __syncthreads();
  #pragma unroll 4
  for (int kp=0;kp<128;kp++){
    unsigned w0 = Wp[kp*512 + tid];
    unsigned w1 = Wp[kp*512 + tid + 256];
    #pragma unroll
    for (int r=0;r<32;r++){
      unsigned xv = xt[r][kp];
      acc0[r] = dot2(xv, w0, acc0[r]);
      acc1[r] = dot2(xv, w1, acc1[r]);
    }
  }
  float wb0 = Wb[tid], wb1 = Wb[tid+256];
  unsigned* o = wxp + ((size_t)(b*2048 + sb*32))*256;
  #pragma unroll
  for (int r=0;r<32;r++)
    o[r*256 + tid] = pkf16(acc0[r]+wb0, acc1[r]+wb1);
}

// ---------------------------------------------------------------------------
// R: sequential scan. 64 blocks x 512 threads. 2 waves/SIMD.
// LDS: utail 128 KB + h 1 KB + ptab 8 KB + rbuf = ~137.3 KB
// ---------------------------------------------------------------------------
__global__ __launch_bounds__(512) void rnn_scan(const uint4* __restrict__ UrP,
                                                const uint4* __restrict__ UtP,
                                                const unsigned* __restrict__ wxp,
                                                const float* __restrict__ Ub,
                                                const float* __restrict__ Vw,
                                                const float* __restrict__ Vb,
                                                float* __restrict__ out){
  __shared__ __align__(16) _Float16 harr[512];   // h, read as uint4
  __shared__ uint4 utail[NTP*512];               // 128 KB
  __shared__ float ptab[4*512];                  // partials [kq][col]
  __shared__ float rbuf[16];
  const int t  = threadIdx.x;
  const int b  = blockIdx.x;
  const int kq = t >> 7;

  uint4 ureg[NRP];                               // 192 arch VGPRs
  #pragma unroll
  for (int j=0;j<NRP;j++) ureg[j] = UrP[j*512 + t];
  #pragma unroll
  for (int i=0;i<NTP;i++) utail[i*512 + t] = UtP[i*512 + t];
  harr[t] = (_Float16)0.f;                       // h0 = 0 (t<512 covers all)
  const float ub_c = Ub[t];                      // this thread's reduce column
  const unsigned* wxb = wxp + (size_t)b*2048*256;
  const int wxoff = t & 255;
  unsigned wc = wxb[wxoff];                      // wx[t=0]
  unsigned wn = wxb[256 + wxoff];                // wx[t=1]
  __syncthreads();

  // broadcast h chunk for this thread's k-quarter
  const uint4* hqv = (const uint4*)((const unsigned*)harr + 64*kq);
  float hf = 0.f;                                // final h for epilogue

  #pragma unroll 1
  for (int ts=0; ts<2048; ts++){
    // prefetch wx two steps ahead
    unsigned wuse = wc;
    wc = wn;
    int tn = (ts+2 < 2048) ? (ts+2) : 2047;
    wn = wxb[tn*256 + wxoff];

    float a0=0.f, a1=0.f, a2=0.f, a3=0.f;        // 4 columns
    #pragma unroll
    for (int i=0;i<NRP/4;i++){                   // VGPR-resident pairs
      uint4 hv = hqv[i];                         // pairs 4i..4i+3 (broadcast)
      uint4 u0 = ureg[4*i+0], u1 = ureg[4*i+1];
      uint4 u2 = ureg[4*i+2], u3 = ureg[4*i+3];
      a0 = dot2(u0.x, hv.x, a0); a1 = dot2(u0.y, hv.x, a1);
      a2 = dot2(u0.z, hv.x, a2); a3 = dot2(u0.w, hv.x, a3);
      a0 = dot2(u1.x, hv.y, a0); a1 = dot2(u1.y, hv.y, a1);
      a2 = dot2(u1.z, hv.y, a2); a3 = dot2(u1.w, hv.y, a3);
      a0 = dot2(u2.x, hv.z, a0); a1 = dot2(u2.y, hv.z, a1);
      a2 = dot2(u2.z, hv.z, a2); a3 = dot2(u2.w, hv.z, a3);
      a0 = dot2(u3.x, hv.w, a0); a1 = dot2(u3.y, hv.w, a1);
      a2 = dot2(u3.z, hv.w, a2); a3 = dot2(u3.w, hv.w, a3);
    }
    #pragma unroll
    for (int i=0;i<NTP/4;i++){                   // LDS-resident pairs
      uint4 hv = hqv[NRP/4 + i];
      uint4 u0 = utail[(4*i+0)*512+t], u1 = utail[(4*i+1)*512+t];
      uint4 u2 = utail[(4*i+2)*512+t], u3 = utail[(4*i+3)*512+t];
      a0 = dot2(u0.x, hv.x, a0); a1 = dot2(u0.y, hv.x, a1);
      a2 = dot2(u0.z, hv.x, a2); a3 = dot2(u0.w, hv.x, a3);
      a0 = dot2(u1.x, hv.y, a0); a1 = dot2(u1.y, hv.y, a1);
      a2 = dot2(u1.z, hv.y, a2); a3 = dot2(u1.w, hv.y, a3);
      a0 = dot2(u2.x, hv.z, a0); a1 = dot2(u2.y, hv.z, a1);
      a2 = dot2(u2.z, hv.z, a2); a3 = dot2(u2.w, hv.z, a3);
      a0 = dot2(u3.x, hv.w, a0); a1 = dot2(u3.y, hv.w, a1);
      a2 = dot2(u3.z, hv.w, a2); a3 = dot2(u3.w, hv.w, a3);
    }
    // partials: ptab[kq][col], stride-1 per wave -> conflict-free
    {
      int cp = t & 127;
      ptab[kq*512 + cp      ] = a0;
      ptab[kq*512 + cp + 128] = a1;
      ptab[kq*512 + cp + 256] = a2;
      ptab[kq*512 + cp + 384] = a3;
    }
    __syncthreads();                             // ptab visible; h reads done
    // reduce: thread t owns column t
    {
      float s = ptab[t] + ptab[512+t] + ptab[1024+t] + ptab[1536+t];
      U32H2 wv; wv.u = wuse;
      float wxe = (float)wv.f[t>>8];
      float pre = s + wxe + ub_c;
      hf = 1.f - 2.f/(__expf(2.f*pre) + 1.f);    // tanh, saturates cleanly
      harr[t] = (_Float16)hf;
    }
    __syncthreads();                             // h visible for next step
  }

  // epilogue: out[b,:] = sigmoid(h_T @ V + Vb); thread t holds h_T[t]
  float p0 = hf*Vw[2*t], p1 = hf*Vw[2*t+1];
  #pragma unroll
  for (int off=32; off>0; off>>=1){
    p0 += __shfl_down(p0, off);
    p1 += __shfl_down(p1, off);
  }
  if ((t & 63) == 0){
    rbuf[(t>>6)*2]   = p0;
    rbuf[(t>>6)*2+1] = p1;
  }
  __syncthreads();
  if (t == 0){
    float s0 = Vb[0], s1 = Vb[1];
    #pragma unroll
    for (int w=0;w<8;w++){ s0 += rbuf[2*w]; s1 += rbuf[2*w+1]; }
    out[2*b]   = 1.f/(1.f + __expf(-s0));
    out[2*b+1] = 1.f/(1.f + __expf(-s1));
  }
}

// ---------------------------------------------------------------------------
extern "C" void kernel_launch(void* const* d_in, const int* in_sizes, int n_in,
                              void* d_out, int out_size, void* d_ws, size_t ws_size,
                              hipStream_t stream) {
  const float* x  = (const float*)d_in[0];   // [64,2048,256]
  const float* Ww = (const float*)d_in[1];   // [256,512]
  const float* Wb = (const float*)d_in[2];   // [512]
  const float* Uw = (const float*)d_in[3];   // [512,512]
  const float* Ub = (const float*)d_in[4];   // [512]
  const float* Vw = (const float*)d_in[5];   // [512,2]
  const float* Vb = (const float*)d_in[6];   // [2]
  float* out = (float*)d_out;                // [64,2]

  char* ws = (char*)d_ws;
  unsigned* wxp = (unsigned*)ws;                               // 134,217,728 B
  unsigned* Wp  = (unsigned*)(ws + 134217728);                 //     262,144 B
  uint4*    UrP = (uint4*)   (ws + 134217728 + 262144);        // 48*512*16 B
  uint4*    UtP = (uint4*)   (ws + 134217728 + 262144 + (size_t)NRP*512*16);

  prep_pack<<<256, 256, 0, stream>>>(Ww, Uw, Wp, UrP, UtP);
  gemm_wx  <<<4096, 256, 0, stream>>>(x, Wp, Wb, wxp);
  rnn_scan <<<64, 512, 0, stream>>>(UrP, UtP, wxp, Ub, Vw, Vb, out);
}